// Round 1
// baseline (241.069 us; speedup 1.0000x reference)
//
#include <hip/hip_runtime.h>

// Problem constants (fixed by the reference)
#define BN 16
#define HN 128
#define WN 128
#define CN 64
#define HO 64
#define WO 64
#define C4 16                         // float4s per channel slice
#define ROW4 (WN * C4)                // 2048 float4 per input row
#define OUTQ (BN * HO * WO * C4)      // 1,048,576 float4 per output tensor

// Native vector type accepted by __builtin_nontemporal_{load,store}
typedef float f32x4 __attribute__((ext_vector_type(4)));

// Quaternion norm, matching the reference bit-exactly:
//   sqrt(((x0^2 + x1^2) + x2^2) + x3^2), no FMA contraction.
__device__ __forceinline__ f32x4 qnorm4(const f32x4 a, const f32x4 b,
                                        const f32x4 c, const f32x4 d) {
#pragma clang fp contract(off)
    f32x4 r;
    r.x = sqrtf(((a.x * a.x + b.x * b.x) + c.x * c.x) + d.x * d.x);
    r.y = sqrtf(((a.y * a.y + b.y * b.y) + c.y * c.y) + d.y * d.y);
    r.z = sqrtf(((a.z * a.z + b.z * b.z) + c.z * c.z) + d.z * d.z);
    r.w = sqrtf(((a.w * a.w + b.w * b.w) + c.w * c.w) + d.w * d.w);
    return r;
}

__device__ __forceinline__ f32x4 ntload(const f32x4* __restrict__ p) {
    // Inputs are single-use -> evict-first hint, don't thrash L2.
    return __builtin_nontemporal_load(p);
}

// One step of the first-max argmax chain (strict > keeps the EARLIER
// window element, matching tf.nn.max_pool_with_argmax / jnp.argmax).
// Window flatten order is (dh,dw) = (0,0),(0,1),(1,0),(1,1).
#define STEP1(f, nn, b0, b1, b2, b3)                                           \
    do {                                                                       \
        bool m = (nn).f > bn.f;                                                \
        bn.f = m ? (nn).f : bn.f;                                              \
        s0.f = m ? (b0).f : s0.f;                                              \
        s1.f = m ? (b1).f : s1.f;                                              \
        s2.f = m ? (b2).f : s2.f;                                              \
        s3.f = m ? (b3).f : s3.f;                                              \
    } while (0)

#define STEP(nn, b0, b1, b2, b3)                                               \
    do {                                                                       \
        STEP1(x, nn, b0, b1, b2, b3);                                          \
        STEP1(y, nn, b0, b1, b2, b3);                                          \
        STEP1(z, nn, b0, b1, b2, b3);                                          \
        STEP1(w, nn, b0, b1, b2, b3);                                          \
    } while (0)

// One thread per OUTPUT f32x4 (t == output index directly). Each thread
// owns the full 2x2 window for its 4 channels:
//   - 16 wave-coalesced loads (4 arrays x 2 rows x 2 cols), 16 KB in
//     flight per wave (2x the previous kernel)
//   - no cross-lane shuffles, no lgkmcnt bubble, no divergent store:
//     every lane stores a full f32x4 to each of the 4 outputs (1 KB/instr)
// Per-instruction load pattern: lane l -> byte (l>>4)*512 + (l&15)*16,
// i.e. 4 x 256B contiguous segments; the paired col1 load covers the
// complementary 256B segments, so every 64B line is requested exactly once.
__global__ __launch_bounds__(256) void maxnorm_pool_kernel(
    const f32x4* __restrict__ x0, const f32x4* __restrict__ x1,
    const f32x4* __restrict__ x2, const f32x4* __restrict__ x3,
    f32x4* __restrict__ out) {
    const int t = blockIdx.x * 256 + threadIdx.x;   // == output f32x4 index
    const int c4 = t & (C4 - 1);
    const int wo = (t >> 4) & (WO - 1);
    const int row = t >> 10;                        // b*HO + ho
    const int ho = row & (HO - 1);
    const int b  = row >> 6;

    // Input f32x4 indices of the 2x2 window (row-major h then w).
    const int g00 = (b * HN + 2 * ho) * ROW4 + wo * (2 * C4) + c4;
    const int g01 = g00 + C4;          // (h0, w1)
    const int g10 = g00 + ROW4;        // (h1, w0)
    const int g11 = g10 + C4;          // (h1, w1)

    // Issue all 16 loads up front (independent; compiler waits per-use).
    f32x4 a0p0 = ntload(x0 + g00), a1p0 = ntload(x1 + g00);
    f32x4 a2p0 = ntload(x2 + g00), a3p0 = ntload(x3 + g00);
    f32x4 a0p1 = ntload(x0 + g01), a1p1 = ntload(x1 + g01);
    f32x4 a2p1 = ntload(x2 + g01), a3p1 = ntload(x3 + g01);
    f32x4 a0p2 = ntload(x0 + g10), a1p2 = ntload(x1 + g10);
    f32x4 a2p2 = ntload(x2 + g10), a3p2 = ntload(x3 + g10);
    f32x4 a0p3 = ntload(x0 + g11), a1p3 = ntload(x1 + g11);
    f32x4 a2p3 = ntload(x2 + g11), a3p3 = ntload(x3 + g11);

    f32x4 n0 = qnorm4(a0p0, a1p0, a2p0, a3p0);
    f32x4 n1 = qnorm4(a0p1, a1p1, a2p1, a3p1);
    f32x4 n2 = qnorm4(a0p2, a1p2, a2p2, a3p2);
    f32x4 n3 = qnorm4(a0p3, a1p3, a2p3, a3p3);

    // First-max argmax chain in window order, selecting all 4 components.
    f32x4 bn = n0, s0 = a0p0, s1 = a1p0, s2 = a2p0, s3 = a3p0;
    STEP(n1, a0p1, a1p1, a2p1, a3p1);
    STEP(n2, a0p2, a1p2, a2p2, a3p2);
    STEP(n3, a0p3, a1p3, a2p3, a3p3);

    // Full-wave contiguous stores (output never re-read in-kernel).
    __builtin_nontemporal_store(s0, out + t);
    __builtin_nontemporal_store(s1, out + OUTQ + t);
    __builtin_nontemporal_store(s2, out + 2 * OUTQ + t);
    __builtin_nontemporal_store(s3, out + 3 * OUTQ + t);
}

extern "C" void kernel_launch(void* const* d_in, const int* in_sizes, int n_in,
                              void* d_out, int out_size, void* d_ws, size_t ws_size,
                              hipStream_t stream) {
    const f32x4* x0 = (const f32x4*)d_in[0];
    const f32x4* x1 = (const f32x4*)d_in[1];
    const f32x4* x2 = (const f32x4*)d_in[2];
    const f32x4* x3 = (const f32x4*)d_in[3];
    f32x4* out = (f32x4*)d_out;

    const int total_threads = OUTQ;            // 1,048,576 (one per output f32x4)
    const int block = 256;
    const int grid = total_threads / block;    // 4096
    maxnorm_pool_kernel<<<grid, block, 0, stream>>>(x0, x1, x2, x3, out);
}